// Round 1
// baseline (183.910 us; speedup 1.0000x reference)
//
#include <hip/hip_runtime.h>
#include <hip/hip_bf16.h>
#include <math.h>

#define NN 8192
#define EE 128

static constexpr float INV_T = 1.0f / 0.07f;

typedef __attribute__((ext_vector_type(8))) short fragAB;   // 8 bf16 = 4 VGPRs
typedef __attribute__((ext_vector_type(4))) float f32x4;

__device__ inline ushort f32_to_bf16_bits(float x) {
  union { float f; unsigned u; } c; c.f = x;
  unsigned u = c.u;
  u += 0x7fffu + ((u >> 16) & 1u);   // round-to-nearest-even
  return (ushort)(u >> 16);
}

// fp32 -> bf16 conversion for both embedding matrices; A is pre-scaled by 1/temperature.
__global__ void lsl_cvt_kernel(const float* __restrict__ A, const float* __restrict__ T,
                               ushort* __restrict__ Ab, ushort* __restrict__ Tb) {
  int i = (blockIdx.x * blockDim.x + threadIdx.x) * 4;
  float4 a = *reinterpret_cast<const float4*>(A + i);
  float4 t = *reinterpret_cast<const float4*>(T + i);
  ushort4 oa, ot;
  oa.x = f32_to_bf16_bits(a.x * INV_T); oa.y = f32_to_bf16_bits(a.y * INV_T);
  oa.z = f32_to_bf16_bits(a.z * INV_T); oa.w = f32_to_bf16_bits(a.w * INV_T);
  ot.x = f32_to_bf16_bits(t.x); ot.y = f32_to_bf16_bits(t.y);
  ot.z = f32_to_bf16_bits(t.z); ot.w = f32_to_bf16_bits(t.w);
  *reinterpret_cast<ushort4*>(Ab + i) = oa;
  *reinterpret_cast<ushort4*>(Tb + i) = ot;
}

// One 128x128 tile of S per workgroup (4 waves, each 64x64 via 4x4 fragments of 16x16x32).
// Emits per-row (over this tile's 64-col block) and per-col (over 64-row block) online
// logsumexp partials (m, s), plus the diagonal values.
__global__ void lsl_tile_kernel(const ushort* __restrict__ Ab, const ushort* __restrict__ Tb,
                                const int* __restrict__ fids,
                                float2* __restrict__ rowp, float2* __restrict__ colp,
                                float* __restrict__ diag) {
  const int tn = blockIdx.x, tm = blockIdx.y;
  const int lane = threadIdx.x & 63;
  const int wid  = threadIdx.x >> 6;
  const int wm = wid >> 1, wn = wid & 1;
  const int rbase = tm * 128 + wm * 64;
  const int cbase = tn * 128 + wn * 64;
  const int lr = lane & 15, lg = lane >> 4;

  f32x4 acc[4][4] = {};   // [fm][fn], D layout: col = lane&15, row = (lane>>4)*4 + reg

#pragma unroll
  for (int ks = 0; ks < 4; ++ks) {
    const int koff = ks * 32 + lg * 8;
    fragAB a[4], b[4];
#pragma unroll
    for (int f = 0; f < 4; ++f) {
      a[f] = *reinterpret_cast<const fragAB*>(Ab + (size_t)(rbase + f * 16 + lr) * EE + koff);
      b[f] = *reinterpret_cast<const fragAB*>(Tb + (size_t)(cbase + f * 16 + lr) * EE + koff);
    }
#pragma unroll
    for (int fm = 0; fm < 4; ++fm)
#pragma unroll
      for (int fn = 0; fn < 4; ++fn)
        acc[fm][fn] = __builtin_amdgcn_mfma_f32_16x16x32_bf16(a[fm], b[fn], acc[fm][fn], 0, 0, 0);
  }

  // fids for my rows (4 per frag-row, contiguous int4) and my cols (1 per frag-col)
  int fr[4][4], fc[4];
#pragma unroll
  for (int fm = 0; fm < 4; ++fm) {
    int4 v4 = *reinterpret_cast<const int4*>(fids + rbase + fm * 16 + lg * 4);
    fr[fm][0] = v4.x; fr[fm][1] = v4.y; fr[fm][2] = v4.z; fr[fm][3] = v4.w;
  }
#pragma unroll
  for (int fn = 0; fn < 4; ++fn) fc[fn] = fids[cbase + fn * 16 + lr];

  // mask (fid equality, diagonal kept) + diagonal extraction
#pragma unroll
  for (int fm = 0; fm < 4; ++fm)
#pragma unroll
    for (int r = 0; r < 4; ++r) {
      const int rowg = rbase + fm * 16 + lg * 4 + r;
#pragma unroll
      for (int fn = 0; fn < 4; ++fn) {
        const int colg = cbase + fn * 16 + lr;
        float v = acc[fm][fn][r];
        if (rowg == colg) diag[rowg] = v;
        bool valid = (fr[fm][r] != fc[fn]) || (rowg == colg);
        acc[fm][fn][r] = valid ? v : -INFINITY;
      }
    }

  // row partials: reduce over this wave's 64 cols (in-lane over fn, butterfly over 16 lanes)
  const int rblk = tn * 2 + wn;
#pragma unroll
  for (int fm = 0; fm < 4; ++fm)
#pragma unroll
    for (int r = 0; r < 4; ++r) {
      float mx = acc[fm][0][r];
#pragma unroll
      for (int fn = 1; fn < 4; ++fn) mx = fmaxf(mx, acc[fm][fn][r]);
#pragma unroll
      for (int d = 1; d < 16; d <<= 1) mx = fmaxf(mx, __shfl_xor(mx, d));
      float s = 0.f;
#pragma unroll
      for (int fn = 0; fn < 4; ++fn) {
        float v = acc[fm][fn][r];
        if (v != -INFINITY) s += __expf(v - mx);
      }
#pragma unroll
      for (int d = 1; d < 16; d <<= 1) s += __shfl_xor(s, d);
      if (lr == 0)
        rowp[(size_t)rblk * NN + (rbase + fm * 16 + lg * 4 + r)] = make_float2(mx, s);
    }

  // col partials: reduce over this wave's 64 rows (in-lane over fm,r; butterfly over groups)
  const int cblk = tm * 2 + wm;
#pragma unroll
  for (int fn = 0; fn < 4; ++fn) {
    float mx = -INFINITY;
#pragma unroll
    for (int fm = 0; fm < 4; ++fm)
#pragma unroll
      for (int r = 0; r < 4; ++r) mx = fmaxf(mx, acc[fm][fn][r]);
    mx = fmaxf(mx, __shfl_xor(mx, 16));
    mx = fmaxf(mx, __shfl_xor(mx, 32));
    float s = 0.f;
#pragma unroll
    for (int fm = 0; fm < 4; ++fm)
#pragma unroll
      for (int r = 0; r < 4; ++r) {
        float v = acc[fm][fn][r];
        if (v != -INFINITY) s += __expf(v - mx);
      }
    s += __shfl_xor(s, 16);
    s += __shfl_xor(s, 32);
    if (lg == 0)
      colp[(size_t)cblk * NN + (cbase + fn * 16 + lr)] = make_float2(mx, s);
  }
}

// Merge 128 online-softmax partials per row and per column, form per-sample loss,
// block-reduce to 32 partial sums.
__global__ void lsl_merge_kernel(const float2* __restrict__ rowp, const float2* __restrict__ colp,
                                 const float* __restrict__ diag, float* __restrict__ bsum) {
  const int i = blockIdx.x * 256 + threadIdx.x;
  float m = -INFINITY, s = 0.f;
  for (int b = 0; b < 128; ++b) {
    float2 p = rowp[(size_t)b * NN + i];
    if (p.y > 0.f) {
      if (p.x > m) { s = s * __expf(m - p.x) + p.y; m = p.x; }
      else s += p.y * __expf(p.x - m);
    }
  }
  float v = m + __logf(s);
  m = -INFINITY; s = 0.f;
  for (int b = 0; b < 128; ++b) {
    float2 p = colp[(size_t)b * NN + i];
    if (p.y > 0.f) {
      if (p.x > m) { s = s * __expf(m - p.x) + p.y; m = p.x; }
      else s += p.y * __expf(p.x - m);
    }
  }
  v += m + __logf(s) - 2.f * diag[i];

  for (int d = 1; d < 64; d <<= 1) v += __shfl_xor(v, d);
  __shared__ float red[4];
  if ((threadIdx.x & 63) == 0) red[threadIdx.x >> 6] = v;
  __syncthreads();
  if (threadIdx.x == 0) bsum[blockIdx.x] = red[0] + red[1] + red[2] + red[3];
}

__global__ void lsl_final_kernel(const float* __restrict__ bsum, float* __restrict__ out) {
  float v = (threadIdx.x < 32) ? bsum[threadIdx.x] : 0.f;
  for (int d = 1; d < 64; d <<= 1) v += __shfl_xor(v, d);
  if (threadIdx.x == 0) out[0] = v / (float)NN;
}

extern "C" void kernel_launch(void* const* d_in, const int* in_sizes, int n_in,
                              void* d_out, int out_size, void* d_ws, size_t ws_size,
                              hipStream_t stream) {
  const float* A = (const float*)d_in[0];
  const float* T = (const float*)d_in[1];
  const int* fids = (const int*)d_in[2];
  float* out = (float*)d_out;
  char* ws = (char*)d_ws;

  // workspace layout (all offsets 16B-aligned):
  //   [0,   2MB)        A bf16 (pre-scaled by 1/temp)
  //   [2MB, 4MB)        T bf16
  //   [4MB, 4MB+32KB)   diag fp32
  //   [.., +8MB)        row partials  float2[128][8192]
  //   [.., +8MB)        col partials  float2[128][8192]
  //   [.., +128B)       block sums
  ushort* Ab  = (ushort*)ws;
  ushort* Tb  = (ushort*)(ws + (size_t)NN * EE * 2);
  float* diag = (float*)(ws + (size_t)NN * EE * 4);
  float2* rowp = (float2*)(ws + (size_t)NN * EE * 4 + (size_t)NN * 4);
  float2* colp = (float2*)(ws + (size_t)NN * EE * 4 + (size_t)NN * 4 + (size_t)128 * NN * 8);
  float* bsum = (float*)(ws + (size_t)NN * EE * 4 + (size_t)NN * 4 + (size_t)256 * NN * 8);

  hipLaunchKernelGGL(lsl_cvt_kernel, dim3(NN * EE / 4 / 256), dim3(256), 0, stream, A, T, Ab, Tb);
  hipLaunchKernelGGL(lsl_tile_kernel, dim3(64, 64), dim3(256), 0, stream, Ab, Tb, fids, rowp, colp, diag);
  hipLaunchKernelGGL(lsl_merge_kernel, dim3(NN / 256), dim3(256), 0, stream, rowp, colp, diag, bsum);
  hipLaunchKernelGGL(lsl_final_kernel, dim3(1), dim3(64), 0, stream, bsum, out);
}

// Round 2
// 150.155 us; speedup vs baseline: 1.2248x; 1.2248x over previous
//
#include <hip/hip_runtime.h>
#include <hip/hip_bf16.h>
#include <math.h>

#define NN 8192
#define EE 128

static constexpr float INV_T = 1.0f / 0.07f;
static constexpr float LOG2E = 1.4426950408889634f;
static constexpr float LN2   = 0.6931471805599453f;
static constexpr float SENT  = -3.0e38f;

typedef __attribute__((ext_vector_type(8))) short fragAB;   // 8 bf16
typedef __attribute__((ext_vector_type(4))) float f32x4;

__device__ inline float fexp2(float x) { float r; asm("v_exp_f32 %0, %1" : "=v"(r) : "v"(x)); return r; }
__device__ inline float flog2(float x) { float r; asm("v_log_f32 %0, %1" : "=v"(r) : "v"(x)); return r; }

template<int CTRL>
__device__ inline float dpp_f(float x) {
  return __builtin_bit_cast(float,
      __builtin_amdgcn_update_dpp(0, __builtin_bit_cast(int, x), CTRL, 0xf, 0xf, true));
}
// butterfly over each 16-lane group: xor1, xor2, half_mirror(==xor4 once quads uniform),
// mirror(==xor8 once 8-groups uniform). All lanes end with the group result.
__device__ inline float red16_max(float x) {
  x = fmaxf(x, dpp_f<0xB1>(x));    // quad_perm [1,0,3,2]
  x = fmaxf(x, dpp_f<0x4E>(x));    // quad_perm [2,3,0,1]
  x = fmaxf(x, dpp_f<0x141>(x));   // row_half_mirror
  x = fmaxf(x, dpp_f<0x140>(x));   // row_mirror
  return x;
}
__device__ inline float red16_add(float x) {
  x += dpp_f<0xB1>(x); x += dpp_f<0x4E>(x); x += dpp_f<0x141>(x); x += dpp_f<0x140>(x);
  return x;
}

__device__ inline ushort f32_to_bf16_bits(float x) {
  union { float f; unsigned u; } c; c.f = x;
  unsigned u = c.u;
  u += 0x7fffu + ((u >> 16) & 1u);   // RNE
  return (ushort)(u >> 16);
}

// fp32 -> bf16 for both matrices (A pre-scaled by 1/temp * log2e so MFMA scores are in
// log2 units), plus exact fp32 diagonal dot products.
__global__ void lsl_cvt_kernel(const float* __restrict__ A, const float* __restrict__ T,
                               ushort* __restrict__ Ab, ushort* __restrict__ Tb,
                               float* __restrict__ diag) {
  const int t = blockIdx.x * 256 + threadIdx.x;
  const int i = t * 4;
  float4 a = *reinterpret_cast<const float4*>(A + i);
  float4 tt = *reinterpret_cast<const float4*>(T + i);
  ushort4 oa, ot;
  const float SC = INV_T * LOG2E;
  oa.x = f32_to_bf16_bits(a.x * SC); oa.y = f32_to_bf16_bits(a.y * SC);
  oa.z = f32_to_bf16_bits(a.z * SC); oa.w = f32_to_bf16_bits(a.w * SC);
  ot.x = f32_to_bf16_bits(tt.x); ot.y = f32_to_bf16_bits(tt.y);
  ot.z = f32_to_bf16_bits(tt.z); ot.w = f32_to_bf16_bits(tt.w);
  *reinterpret_cast<ushort4*>(Ab + i) = oa;
  *reinterpret_cast<ushort4*>(Tb + i) = ot;

  // diagonal: 32 consecutive lanes cover one row of 128 elements
  float pd = a.x * tt.x + a.y * tt.y + a.z * tt.z + a.w * tt.w;
  pd += __shfl_xor(pd, 1); pd += __shfl_xor(pd, 2); pd += __shfl_xor(pd, 4);
  pd += __shfl_xor(pd, 8); pd += __shfl_xor(pd, 16);
  if ((threadIdx.x & 31) == 0) diag[i >> 7] = pd * INV_T;   // nat units
}

// One 128x128 tile of S' (= S * log2e) per workgroup; 4 waves of 64x64.
// Emits per-64-block row and col logsumexp partials (m, s) in log2 domain.
__global__ __launch_bounds__(256) void
lsl_tile_kernel(const ushort* __restrict__ Ab, const ushort* __restrict__ Tb,
                const int* __restrict__ fids,
                float2* __restrict__ rowp, float2* __restrict__ colp) {
  const int tn = blockIdx.x, tm = blockIdx.y;
  const int lane = threadIdx.x & 63;
  const int wid  = threadIdx.x >> 6;
  const int wm = wid >> 1, wn = wid & 1;
  const int rbase = tm * 128 + wm * 64;
  const int cbase = tn * 128 + wn * 64;
  const int lr = lane & 15, lg = lane >> 4;

  f32x4 acc[4][4] = {};   // D layout: col = lane&15, row = (lane>>4)*4 + reg

#pragma unroll
  for (int ks = 0; ks < 4; ++ks) {
    const int koff = ks * 32 + lg * 8;
    fragAB a[4], b[4];
#pragma unroll
    for (int f = 0; f < 4; ++f) {
      a[f] = *reinterpret_cast<const fragAB*>(Ab + (size_t)(rbase + f * 16 + lr) * EE + koff);
      b[f] = *reinterpret_cast<const fragAB*>(Tb + (size_t)(cbase + f * 16 + lr) * EE + koff);
    }
#pragma unroll
    for (int fm = 0; fm < 4; ++fm)
#pragma unroll
      for (int fn = 0; fn < 4; ++fn)
        acc[fm][fn] = __builtin_amdgcn_mfma_f32_16x16x32_bf16(a[fm], b[fn], acc[fm][fn], 0, 0, 0);
  }

  int fr[4][4], fc[4];
#pragma unroll
  for (int fm = 0; fm < 4; ++fm) {
    int4 v4 = *reinterpret_cast<const int4*>(fids + rbase + fm * 16 + lg * 4);
    fr[fm][0] = v4.x; fr[fm][1] = v4.y; fr[fm][2] = v4.z; fr[fm][3] = v4.w;
  }
#pragma unroll
  for (int fn = 0; fn < 4; ++fn) fc[fn] = fids[cbase + fn * 16 + lr];

  // branchless mask -> sentinel; diagonal kept (only possible when rbase == cbase)
  if (rbase == cbase) {
#pragma unroll
    for (int fm = 0; fm < 4; ++fm)
#pragma unroll
      for (int fn = 0; fn < 4; ++fn)
#pragma unroll
        for (int r = 0; r < 4; ++r) {
          bool keep = (fr[fm][r] != fc[fn]) || (fm == fn && lr == lg * 4 + r);
          acc[fm][fn][r] = keep ? acc[fm][fn][r] : SENT;
        }
  } else {
#pragma unroll
    for (int fm = 0; fm < 4; ++fm)
#pragma unroll
      for (int fn = 0; fn < 4; ++fn)
#pragma unroll
        for (int r = 0; r < 4; ++r)
          acc[fm][fn][r] = (fr[fm][r] != fc[fn]) ? acc[fm][fn][r] : SENT;
  }

  // row partials over this wave's 64 cols
  const int rblk = tn * 2 + wn;
#pragma unroll
  for (int fm = 0; fm < 4; ++fm)
#pragma unroll
    for (int r = 0; r < 4; ++r) {
      float mx = fmaxf(fmaxf(acc[fm][0][r], acc[fm][1][r]), fmaxf(acc[fm][2][r], acc[fm][3][r]));
      mx = red16_max(mx);
      float s = fexp2(acc[fm][0][r] - mx) + fexp2(acc[fm][1][r] - mx)
              + fexp2(acc[fm][2][r] - mx) + fexp2(acc[fm][3][r] - mx);
      s = red16_add(s);
      if (lr == 0)
        rowp[(size_t)rblk * NN + (rbase + fm * 16 + lg * 4 + r)] = make_float2(mx, s);
    }

  // col partials over this wave's 64 rows
  const int cblk = tm * 2 + wm;
#pragma unroll
  for (int fn = 0; fn < 4; ++fn) {
    float mx = SENT;
#pragma unroll
    for (int fm = 0; fm < 4; ++fm)
#pragma unroll
      for (int r = 0; r < 4; ++r) mx = fmaxf(mx, acc[fm][fn][r]);
    mx = fmaxf(mx, __shfl_xor(mx, 16));
    mx = fmaxf(mx, __shfl_xor(mx, 32));
    float s = 0.f;
#pragma unroll
    for (int fm = 0; fm < 4; ++fm)
#pragma unroll
      for (int r = 0; r < 4; ++r) s += fexp2(acc[fm][fn][r] - mx);
    s += __shfl_xor(s, 16);
    s += __shfl_xor(s, 32);
    if (lg == 0)
      colp[(size_t)cblk * NN + (cbase + fn * 16 + lr)] = make_float2(mx, s);
  }
}

// Merge 128 partials per row and per column: independent max pass, then FMA pass.
__global__ __launch_bounds__(64) void
lsl_merge_kernel(const float2* __restrict__ rowp, const float2* __restrict__ colp,
                 const float* __restrict__ diag, float* __restrict__ bsum) {
  const int i = blockIdx.x * 64 + threadIdx.x;

  float m = SENT;
#pragma unroll 8
  for (int b = 0; b < 128; ++b) m = fmaxf(m, rowp[(size_t)b * NN + i].x);
  float s = 0.f;
#pragma unroll 8
  for (int b = 0; b < 128; ++b) {
    float2 p = rowp[(size_t)b * NN + i];
    s += p.y * fexp2(p.x - m);
  }
  float v = m + flog2(s);

  float m2 = SENT;
#pragma unroll 8
  for (int b = 0; b < 128; ++b) m2 = fmaxf(m2, colp[(size_t)b * NN + i].x);
  float s2 = 0.f;
#pragma unroll 8
  for (int b = 0; b < 128; ++b) {
    float2 p = colp[(size_t)b * NN + i];
    s2 += p.y * fexp2(p.x - m2);
  }
  v += m2 + flog2(s2);

  float loss = LN2 * v - 2.f * diag[i];
#pragma unroll
  for (int d = 1; d < 64; d <<= 1) loss += __shfl_xor(loss, d);
  if (threadIdx.x == 0) bsum[blockIdx.x] = loss;
}

__global__ void lsl_final_kernel(const float* __restrict__ bsum, float* __restrict__ out) {
  float v = bsum[threadIdx.x] + bsum[threadIdx.x + 64];
#pragma unroll
  for (int d = 1; d < 64; d <<= 1) v += __shfl_xor(v, d);
  if (threadIdx.x == 0) out[0] = v / (float)NN;
}

extern "C" void kernel_launch(void* const* d_in, const int* in_sizes, int n_in,
                              void* d_out, int out_size, void* d_ws, size_t ws_size,
                              hipStream_t stream) {
  const float* A = (const float*)d_in[0];
  const float* T = (const float*)d_in[1];
  const int* fids = (const int*)d_in[2];
  float* out = (float*)d_out;
  char* ws = (char*)d_ws;

  // workspace: Ab 2MB | Tb 2MB | diag 32KB | rowp 8MB | colp 8MB | bsum 512B
  ushort* Ab  = (ushort*)ws;
  ushort* Tb  = (ushort*)(ws + (size_t)NN * EE * 2);
  float* diag = (float*)(ws + (size_t)NN * EE * 4);
  float2* rowp = (float2*)(ws + (size_t)NN * EE * 4 + (size_t)NN * 4);
  float2* colp = (float2*)(ws + (size_t)NN * EE * 4 + (size_t)NN * 4 + (size_t)128 * NN * 8);
  float* bsum = (float*)(ws + (size_t)NN * EE * 4 + (size_t)NN * 4 + (size_t)256 * NN * 8);

  hipLaunchKernelGGL(lsl_cvt_kernel, dim3(NN * EE / 4 / 256), dim3(256), 0, stream, A, T, Ab, Tb, diag);
  hipLaunchKernelGGL(lsl_tile_kernel, dim3(64, 64), dim3(256), 0, stream, Ab, Tb, fids, rowp, colp);
  hipLaunchKernelGGL(lsl_merge_kernel, dim3(NN / 64), dim3(64), 0, stream, rowp, colp, diag, bsum);
  hipLaunchKernelGGL(lsl_final_kernel, dim3(1), dim3(64), 0, stream, bsum, out);
}

// Round 4
// 136.044 us; speedup vs baseline: 1.3518x; 1.1037x over previous
//
#include <hip/hip_runtime.h>
#include <hip/hip_bf16.h>
#include <math.h>

#define NN 8192
#define EE 128

static constexpr float INV_T = 1.0f / 0.07f;
static constexpr float LOG2E = 1.4426950408889634f;
static constexpr float LN2   = 0.6931471805599453f;
static constexpr float SENT  = -3.0e38f;

typedef __attribute__((ext_vector_type(8))) short fragAB;   // 8 bf16
typedef __attribute__((ext_vector_type(4))) float f32x4;

__device__ inline float fexp2(float x) { float r; asm("v_exp_f32 %0, %1" : "=v"(r) : "v"(x)); return r; }
__device__ inline float flog2(float x) { float r; asm("v_log_f32 %0, %1" : "=v"(r) : "v"(x)); return r; }

template<int CTRL>
__device__ inline float dpp_f(float x) {
  return __builtin_bit_cast(float,
      __builtin_amdgcn_update_dpp(0, __builtin_bit_cast(int, x), CTRL, 0xf, 0xf, true));
}
__device__ inline float red16_max(float x) {
  x = fmaxf(x, dpp_f<0xB1>(x));    // quad_perm [1,0,3,2]
  x = fmaxf(x, dpp_f<0x4E>(x));    // quad_perm [2,3,0,1]
  x = fmaxf(x, dpp_f<0x141>(x));   // row_half_mirror
  x = fmaxf(x, dpp_f<0x140>(x));   // row_mirror
  return x;
}
__device__ inline float red16_add(float x) {
  x += dpp_f<0xB1>(x); x += dpp_f<0x4E>(x); x += dpp_f<0x141>(x); x += dpp_f<0x140>(x);
  return x;
}

__device__ inline ushort f32_to_bf16_bits(float x) {
  union { float f; unsigned u; } c; c.f = x;
  unsigned u = c.u;
  u += 0x7fffu + ((u >> 16) & 1u);   // RNE
  return (ushort)(u >> 16);
}

// fp32 -> bf16 (A pre-scaled by 1/temp*log2e so scores are log2-domain),
// plus exact fp32 diagonal dot products (log2 units).
__global__ void lsl_cvt_kernel(const float* __restrict__ A, const float* __restrict__ T,
                               ushort* __restrict__ Ab, ushort* __restrict__ Tb,
                               float* __restrict__ diag) {
  const int t = blockIdx.x * 256 + threadIdx.x;
  const int i = t * 4;
  float4 a = *reinterpret_cast<const float4*>(A + i);
  float4 tt = *reinterpret_cast<const float4*>(T + i);
  ushort4 oa, ot;
  const float SC = INV_T * LOG2E;
  oa.x = f32_to_bf16_bits(a.x * SC); oa.y = f32_to_bf16_bits(a.y * SC);
  oa.z = f32_to_bf16_bits(a.z * SC); oa.w = f32_to_bf16_bits(a.w * SC);
  ot.x = f32_to_bf16_bits(tt.x); ot.y = f32_to_bf16_bits(tt.y);
  ot.z = f32_to_bf16_bits(tt.z); ot.w = f32_to_bf16_bits(tt.w);
  *reinterpret_cast<ushort4*>(Ab + i) = oa;
  *reinterpret_cast<ushort4*>(Tb + i) = ot;

  float pd = a.x * tt.x + a.y * tt.y + a.z * tt.z + a.w * tt.w;
  pd += __shfl_xor(pd, 1); pd += __shfl_xor(pd, 2); pd += __shfl_xor(pd, 4);
  pd += __shfl_xor(pd, 8); pd += __shfl_xor(pd, 16);
  if ((threadIdx.x & 31) == 0) diag[i >> 7] = pd * (INV_T * LOG2E);   // log2 units
}

// WG = 256 rows x 256 cols; wave w owns rows [rbase, rbase+64), iterates 4 col
// sub-tiles of 64, keeping per-row lse state in registers (own-max referenced ->
// no underflow). Col partials computed directly per column (own-max referenced).
// Layouts for contiguous merge: rowp[row][32], colp[col][128].
__global__ __launch_bounds__(256) void
lsl_tile_kernel(const ushort* __restrict__ Ab, const ushort* __restrict__ Tb,
                const int* __restrict__ fids,
                float2* __restrict__ rowp, float2* __restrict__ colp) {
  const int bid = blockIdx.x;
  const int swz = (bid & 7) * 128 + (bid >> 3);   // bijective XCD chunking (1024 WGs)
  const int tm = swz >> 5, tn = swz & 31;
  const int lane = threadIdx.x & 63;
  const int wid  = threadIdx.x >> 6;
  const int rbase = tm * 256 + wid * 64;
  const int lr = lane & 15, lg = lane >> 4;

  int fr[4][4];
#pragma unroll
  for (int fm = 0; fm < 4; ++fm) {
    int4 v4 = *reinterpret_cast<const int4*>(fids + rbase + fm * 16 + lg * 4);
    fr[fm][0] = v4.x; fr[fm][1] = v4.y; fr[fm][2] = v4.z; fr[fm][3] = v4.w;
  }

  float Mrow[4][4], Srow[4][4];
#pragma unroll
  for (int fm = 0; fm < 4; ++fm)
#pragma unroll
    for (int r = 0; r < 4; ++r) { Mrow[fm][r] = SENT; Srow[fm][r] = 0.f; }

  const ushort* abase = Ab + (size_t)(rbase + lr) * EE + lg * 8;
  const int mb = tm * 4 + wid;   // col-partial block id (64-row blocks, 0..127)

#pragma unroll
  for (int st = 0; st < 4; ++st) {
    const int cbase = tn * 256 + st * 64;
    const ushort* bbase = Tb + (size_t)(cbase + lr) * EE + lg * 8;

    int fc[4];
#pragma unroll
    for (int fn = 0; fn < 4; ++fn) fc[fn] = fids[cbase + fn * 16 + lr];

    f32x4 acc[4][4] = {};
#pragma unroll
    for (int ks = 0; ks < 4; ++ks) {
      fragAB av[4], bv[4];
#pragma unroll
      for (int f = 0; f < 4; ++f) {
        av[f] = *reinterpret_cast<const fragAB*>(abase + f * (16 * EE) + ks * 32);
        bv[f] = *reinterpret_cast<const fragAB*>(bbase + f * (16 * EE) + ks * 32);
      }
#pragma unroll
      for (int fm = 0; fm < 4; ++fm)
#pragma unroll
        for (int fn = 0; fn < 4; ++fn)
          acc[fm][fn] = __builtin_amdgcn_mfma_f32_16x16x32_bf16(av[fm], bv[fn], acc[fm][fn], 0, 0, 0);
    }

    // mask -> sentinel (diagonal kept; only possible when rbase == cbase)
    if (rbase == cbase) {
#pragma unroll
      for (int fm = 0; fm < 4; ++fm)
#pragma unroll
        for (int fn = 0; fn < 4; ++fn)
#pragma unroll
          for (int r = 0; r < 4; ++r) {
            bool keep = (fr[fm][r] != fc[fn]) || (fm == fn && lr == lg * 4 + r);
            acc[fm][fn][r] = keep ? acc[fm][fn][r] : SENT;
          }
    } else {
#pragma unroll
      for (int fm = 0; fm < 4; ++fm)
#pragma unroll
        for (int fn = 0; fn < 4; ++fn)
#pragma unroll
          for (int r = 0; r < 4; ++r)
            acc[fm][fn][r] = (fr[fm][r] != fc[fn]) ? acc[fm][fn][r] : SENT;
    }

    // row pass: own-max referenced, online combine into (Mrow, Srow)
#pragma unroll
    for (int fm = 0; fm < 4; ++fm)
#pragma unroll
      for (int r = 0; r < 4; ++r) {
        float m = fmaxf(fmaxf(acc[fm][0][r], acc[fm][1][r]), fmaxf(acc[fm][2][r], acc[fm][3][r]));
        m = red16_max(m);
        float s = fexp2(acc[fm][0][r] - m) + fexp2(acc[fm][1][r] - m)
                + fexp2(acc[fm][2][r] - m) + fexp2(acc[fm][3][r] - m);
        s = red16_add(s);
        float Mn = fmaxf(Mrow[fm][r], m);
        Srow[fm][r] = Srow[fm][r] * fexp2(Mrow[fm][r] - Mn) + s * fexp2(m - Mn);
        Mrow[fm][r] = Mn;
      }

    // col pass: own-max referenced (lane holds 16 rows of its column per fn)
#pragma unroll
    for (int fn = 0; fn < 4; ++fn) {
      float cm = SENT;
#pragma unroll
      for (int fm = 0; fm < 4; ++fm)
#pragma unroll
        for (int r = 0; r < 4; ++r) cm = fmaxf(cm, acc[fm][fn][r]);
      cm = fmaxf(cm, __shfl_xor(cm, 16));
      cm = fmaxf(cm, __shfl_xor(cm, 32));
      float c = 0.f;
#pragma unroll
      for (int fm = 0; fm < 4; ++fm)
#pragma unroll
        for (int r = 0; r < 4; ++r) c += fexp2(acc[fm][fn][r] - cm);
      c += __shfl_xor(c, 16);
      c += __shfl_xor(c, 32);
      if (lg == 0)
        colp[(size_t)(cbase + fn * 16 + lr) * 128 + mb] = make_float2(cm, c);
    }
  }

  // row partial store: one per row, block index = tn
#pragma unroll
  for (int fm = 0; fm < 4; ++fm)
#pragma unroll
    for (int r = 0; r < 4; ++r)
      if (lr == 0)
        rowp[(size_t)(rbase + fm * 16 + lg * 4 + r) * 32 + tn] = make_float2(Mrow[fm][r], Srow[fm][r]);
}

// One wave per sample i: merge 128 col partials (contiguous 1KB) and 32 row
// partials (contiguous 256B), form loss_i, block-reduce.
__global__ __launch_bounds__(256) void
lsl_merge_kernel(const float2* __restrict__ rowp, const float2* __restrict__ colp,
                 const float* __restrict__ diag, float* __restrict__ bsum) {
  const int lane = threadIdx.x & 63;
  const int wid  = threadIdx.x >> 6;
  const int i = blockIdx.x * 4 + wid;

  // col merge: each lane reads 2 float2 (16B)
  float4 cp = *reinterpret_cast<const float4*>(reinterpret_cast<const float*>(colp) + (size_t)i * 256 + lane * 4);
  float m = fmaxf(cp.x, cp.z);
#pragma unroll
  for (int d = 1; d < 64; d <<= 1) m = fmaxf(m, __shfl_xor(m, d));
  float s = cp.y * fexp2(cp.x - m) + cp.w * fexp2(cp.z - m);
#pragma unroll
  for (int d = 1; d < 64; d <<= 1) s += __shfl_xor(s, d);
  float lse = m + flog2(s);

  // row merge: 32 float2 read by 16 lanes (others duplicate)
  float4 rp = *reinterpret_cast<const float4*>(reinterpret_cast<const float*>(rowp) + (size_t)i * 64 + (lane & 15) * 4);
  float m2 = fmaxf(rp.x, rp.z);
  m2 = red16_max(m2);
  float s2 = rp.y * fexp2(rp.x - m2) + rp.w * fexp2(rp.z - m2);
  s2 = red16_add(s2);
  lse += m2 + flog2(s2);

  float loss = lse - 2.f * diag[i];   // log2 units

  __shared__ float l4[4];
  if (lane == 0) l4[wid] = loss;
  __syncthreads();
  if (threadIdx.x == 0) bsum[blockIdx.x] = l4[0] + l4[1] + l4[2] + l4[3];
}

__global__ __launch_bounds__(256) void
lsl_final_kernel(const float* __restrict__ bsum, float* __restrict__ out) {
  float v = 0.f;
#pragma unroll
  for (int k = 0; k < 8; ++k) v += bsum[threadIdx.x + k * 256];
#pragma unroll
  for (int d = 1; d < 64; d <<= 1) v += __shfl_xor(v, d);
  __shared__ float l4[4];
  if ((threadIdx.x & 63) == 0) l4[threadIdx.x >> 6] = v;
  __syncthreads();
  if (threadIdx.x == 0) out[0] = (l4[0] + l4[1] + l4[2] + l4[3]) * (LN2 / (float)NN);
}

extern "C" void kernel_launch(void* const* d_in, const int* in_sizes, int n_in,
                              void* d_out, int out_size, void* d_ws, size_t ws_size,
                              hipStream_t stream) {
  const float* A = (const float*)d_in[0];
  const float* T = (const float*)d_in[1];
  const int* fids = (const int*)d_in[2];
  float* out = (float*)d_out;
  char* ws = (char*)d_ws;

  // ws: Ab 2MB | Tb 2MB | diag 32KB | rowp 2MB | colp 8MB | bsum 8KB
  ushort* Ab  = (ushort*)ws;
  ushort* Tb  = (ushort*)(ws + (size_t)NN * EE * 2);
  float* diag = (float*)(ws + (size_t)NN * EE * 4);
  float2* rowp = (float2*)(ws + (size_t)NN * EE * 4 + (size_t)NN * 4);
  float2* colp = (float2*)(ws + (size_t)NN * EE * 4 + (size_t)NN * 4 + (size_t)NN * 32 * 8);
  float* bsum = (float*)(ws + (size_t)NN * EE * 4 + (size_t)NN * 4 + (size_t)NN * 32 * 8 + (size_t)NN * 128 * 8);

  hipLaunchKernelGGL(lsl_cvt_kernel, dim3(NN * EE / 4 / 256), dim3(256), 0, stream, A, T, Ab, Tb, diag);
  hipLaunchKernelGGL(lsl_tile_kernel, dim3(1024), dim3(256), 0, stream, Ab, Tb, fids, rowp, colp);
  hipLaunchKernelGGL(lsl_merge_kernel, dim3(NN / 4), dim3(256), 0, stream, rowp, colp, diag, bsum);
  hipLaunchKernelGGL(lsl_final_kernel, dim3(1), dim3(256), 0, stream, bsum, out);
}

// Round 5
// 107.006 us; speedup vs baseline: 1.7187x; 1.2714x over previous
//
#include <hip/hip_runtime.h>
#include <hip/hip_bf16.h>
#include <math.h>

#define NN 8192
#define EE 128

static constexpr float INV_T = 1.0f / 0.07f;
static constexpr float LOG2E = 1.4426950408889634f;
static constexpr float LN2   = 0.6931471805599453f;
static constexpr float SENT  = -3.0e38f;

typedef __attribute__((ext_vector_type(8))) short fragAB;   // 8 bf16
typedef __attribute__((ext_vector_type(4))) float f32x4;

__device__ inline float fexp2(float x) { float r; asm("v_exp_f32 %0, %1" : "=v"(r) : "v"(x)); return r; }
__device__ inline float flog2(float x) { float r; asm("v_log_f32 %0, %1" : "=v"(r) : "v"(x)); return r; }

template<int CTRL>
__device__ inline float dpp_f(float x) {
  return __builtin_bit_cast(float,
      __builtin_amdgcn_update_dpp(0, __builtin_bit_cast(int, x), CTRL, 0xf, 0xf, true));
}
__device__ inline float red16_max(float x) {
  x = fmaxf(x, dpp_f<0xB1>(x));    // quad_perm [1,0,3,2]
  x = fmaxf(x, dpp_f<0x4E>(x));    // quad_perm [2,3,0,1]
  x = fmaxf(x, dpp_f<0x141>(x));   // row_half_mirror
  x = fmaxf(x, dpp_f<0x140>(x));   // row_mirror
  return x;
}
__device__ inline float red16_add(float x) {
  x += dpp_f<0xB1>(x); x += dpp_f<0x4E>(x); x += dpp_f<0x141>(x); x += dpp_f<0x140>(x);
  return x;
}

__device__ inline ushort f32_to_bf16_bits(float x) {
  union { float f; unsigned u; } c; c.f = x;
  unsigned u = c.u;
  u += 0x7fffu + ((u >> 16) & 1u);   // RNE
  return (ushort)(u >> 16);
}

// fp32 -> bf16 (A pre-scaled by 1/temp*log2e so scores are log2-domain),
// plus exact fp32 diagonal dot products (log2 units).
__global__ void lsl_cvt_kernel(const float* __restrict__ A, const float* __restrict__ T,
                               ushort* __restrict__ Ab, ushort* __restrict__ Tb,
                               float* __restrict__ diag) {
  const int t = blockIdx.x * 256 + threadIdx.x;
  const int i = t * 4;
  float4 a = *reinterpret_cast<const float4*>(A + i);
  float4 tt = *reinterpret_cast<const float4*>(T + i);
  ushort4 oa, ot;
  const float SC = INV_T * LOG2E;
  oa.x = f32_to_bf16_bits(a.x * SC); oa.y = f32_to_bf16_bits(a.y * SC);
  oa.z = f32_to_bf16_bits(a.z * SC); oa.w = f32_to_bf16_bits(a.w * SC);
  ot.x = f32_to_bf16_bits(tt.x); ot.y = f32_to_bf16_bits(tt.y);
  ot.z = f32_to_bf16_bits(tt.z); ot.w = f32_to_bf16_bits(tt.w);
  *reinterpret_cast<ushort4*>(Ab + i) = oa;
  *reinterpret_cast<ushort4*>(Tb + i) = ot;

  float pd = a.x * tt.x + a.y * tt.y + a.z * tt.z + a.w * tt.w;
  pd += __shfl_xor(pd, 1); pd += __shfl_xor(pd, 2); pd += __shfl_xor(pd, 4);
  pd += __shfl_xor(pd, 8); pd += __shfl_xor(pd, 16);
  if ((threadIdx.x & 31) == 0) diag[i >> 7] = pd * (INV_T * LOG2E);   // log2 units
}

// WG = 128x128 (4 waves in 2x2, one 64x64 sub-tile per wave). Register-lean:
// no persistent online state; fids loaded after the MFMA loop so their live
// range overlaps the dead fragment registers. Partial layouts transposed for
// contiguous merge: rowp[row][128], colp[col][128].
__global__ __launch_bounds__(256, 4) void
lsl_tile_kernel(const ushort* __restrict__ Ab, const ushort* __restrict__ Tb,
                const int* __restrict__ fids,
                float2* __restrict__ rowp, float2* __restrict__ colp) {
  const int bid = blockIdx.x;
  const int swz = (bid & 7) * 512 + (bid >> 3);   // bijective XCD chunking (4096 WGs)
  const int tm = swz >> 6, tn = swz & 63;
  const int lane = threadIdx.x & 63;
  const int wid  = threadIdx.x >> 6;
  const int wm = wid >> 1, wn = wid & 1;
  const int rbase = tm * 128 + wm * 64;
  const int cbase = tn * 128 + wn * 64;
  const int lr = lane & 15, lg = lane >> 4;

  const ushort* abase = Ab + (size_t)(rbase + lr) * EE + lg * 8;
  const ushort* bbase = Tb + (size_t)(cbase + lr) * EE + lg * 8;

  f32x4 acc[4][4] = {};   // D: col = lane&15, row = (lane>>4)*4 + reg

#pragma unroll
  for (int ks = 0; ks < 4; ++ks) {
    fragAB av[4], bv[4];
#pragma unroll
    for (int f = 0; f < 4; ++f) {
      av[f] = *reinterpret_cast<const fragAB*>(abase + f * (16 * EE) + ks * 32);
      bv[f] = *reinterpret_cast<const fragAB*>(bbase + f * (16 * EE) + ks * 32);
    }
#pragma unroll
    for (int fm = 0; fm < 4; ++fm)
#pragma unroll
      for (int fn = 0; fn < 4; ++fn)
        acc[fm][fn] = __builtin_amdgcn_mfma_f32_16x16x32_bf16(av[fm], bv[fn], acc[fm][fn], 0, 0, 0);
  }

  // fids loaded here (post-MFMA) to keep live ranges off the main loop
  int fr[4][4], fc[4];
#pragma unroll
  for (int fm = 0; fm < 4; ++fm) {
    int4 v4 = *reinterpret_cast<const int4*>(fids + rbase + fm * 16 + lg * 4);
    fr[fm][0] = v4.x; fr[fm][1] = v4.y; fr[fm][2] = v4.z; fr[fm][3] = v4.w;
  }
#pragma unroll
  for (int fn = 0; fn < 4; ++fn) fc[fn] = fids[cbase + fn * 16 + lr];

  // branchless mask -> sentinel (diagonal kept; only possible when rbase == cbase)
  if (rbase == cbase) {
#pragma unroll
    for (int fm = 0; fm < 4; ++fm)
#pragma unroll
      for (int fn = 0; fn < 4; ++fn)
#pragma unroll
        for (int r = 0; r < 4; ++r) {
          bool keep = (fr[fm][r] != fc[fn]) || (fm == fn && lr == lg * 4 + r);
          acc[fm][fn][r] = keep ? acc[fm][fn][r] : SENT;
        }
  } else {
#pragma unroll
    for (int fm = 0; fm < 4; ++fm)
#pragma unroll
      for (int fn = 0; fn < 4; ++fn)
#pragma unroll
        for (int r = 0; r < 4; ++r)
          acc[fm][fn][r] = (fr[fm][r] != fc[fn]) ? acc[fm][fn][r] : SENT;
  }

  // row partials over this wave's 64 cols (own-max referenced)
  const int rblk = tn * 2 + wn;
#pragma unroll
  for (int fm = 0; fm < 4; ++fm)
#pragma unroll
    for (int r = 0; r < 4; ++r) {
      float m = fmaxf(fmaxf(acc[fm][0][r], acc[fm][1][r]), fmaxf(acc[fm][2][r], acc[fm][3][r]));
      m = red16_max(m);
      float s = fexp2(acc[fm][0][r] - m) + fexp2(acc[fm][1][r] - m)
              + fexp2(acc[fm][2][r] - m) + fexp2(acc[fm][3][r] - m);
      s = red16_add(s);
      if (lr == 0)
        rowp[(size_t)(rbase + fm * 16 + lg * 4 + r) * 128 + rblk] = make_float2(m, s);
    }

  // col partials over this wave's 64 rows (own-max referenced)
  const int cblk = tm * 2 + wm;
#pragma unroll
  for (int fn = 0; fn < 4; ++fn) {
    float cm = SENT;
#pragma unroll
    for (int fm = 0; fm < 4; ++fm)
#pragma unroll
      for (int r = 0; r < 4; ++r) cm = fmaxf(cm, acc[fm][fn][r]);
    cm = fmaxf(cm, __shfl_xor(cm, 16));
    cm = fmaxf(cm, __shfl_xor(cm, 32));
    float c = 0.f;
#pragma unroll
    for (int fm = 0; fm < 4; ++fm)
#pragma unroll
      for (int r = 0; r < 4; ++r) c += fexp2(acc[fm][fn][r] - cm);
    c += __shfl_xor(c, 16);
    c += __shfl_xor(c, 32);
    if (lg == 0)
      colp[(size_t)(cbase + fn * 16 + lr) * 128 + cblk] = make_float2(cm, c);
  }
}

// One wave per sample i: merge 128 row partials and 128 col partials
// (each a contiguous 1KB read), form loss_i, block-reduce.
__global__ __launch_bounds__(256) void
lsl_merge_kernel(const float2* __restrict__ rowp, const float2* __restrict__ colp,
                 const float* __restrict__ diag, float* __restrict__ bsum) {
  const int lane = threadIdx.x & 63;
  const int wid  = threadIdx.x >> 6;
  const int i = blockIdx.x * 4 + wid;

  float4 rp = *reinterpret_cast<const float4*>(reinterpret_cast<const float*>(rowp) + (size_t)i * 256 + lane * 4);
  float m = fmaxf(rp.x, rp.z);
#pragma unroll
  for (int d = 1; d < 64; d <<= 1) m = fmaxf(m, __shfl_xor(m, d));
  float s = rp.y * fexp2(rp.x - m) + rp.w * fexp2(rp.z - m);
#pragma unroll
  for (int d = 1; d < 64; d <<= 1) s += __shfl_xor(s, d);
  float lse = m + flog2(s);

  float4 cp = *reinterpret_cast<const float4*>(reinterpret_cast<const float*>(colp) + (size_t)i * 256 + lane * 4);
  float m2 = fmaxf(cp.x, cp.z);
#pragma unroll
  for (int d = 1; d < 64; d <<= 1) m2 = fmaxf(m2, __shfl_xor(m2, d));
  float s2 = cp.y * fexp2(cp.x - m2) + cp.w * fexp2(cp.z - m2);
#pragma unroll
  for (int d = 1; d < 64; d <<= 1) s2 += __shfl_xor(s2, d);
  lse += m2 + flog2(s2);

  float loss = lse - 2.f * diag[i];   // log2 units

  __shared__ float l4[4];
  if (lane == 0) l4[wid] = loss;
  __syncthreads();
  if (threadIdx.x == 0) bsum[blockIdx.x] = l4[0] + l4[1] + l4[2] + l4[3];
}

__global__ __launch_bounds__(256) void
lsl_final_kernel(const float* __restrict__ bsum, float* __restrict__ out) {
  float v = 0.f;
#pragma unroll
  for (int k = 0; k < 8; ++k) v += bsum[threadIdx.x + k * 256];
#pragma unroll
  for (int d = 1; d < 64; d <<= 1) v += __shfl_xor(v, d);
  __shared__ float l4[4];
  if ((threadIdx.x & 63) == 0) l4[threadIdx.x >> 6] = v;
  __syncthreads();
  if (threadIdx.x == 0) out[0] = (l4[0] + l4[1] + l4[2] + l4[3]) * (LN2 / (float)NN);
}

extern "C" void kernel_launch(void* const* d_in, const int* in_sizes, int n_in,
                              void* d_out, int out_size, void* d_ws, size_t ws_size,
                              hipStream_t stream) {
  const float* A = (const float*)d_in[0];
  const float* T = (const float*)d_in[1];
  const int* fids = (const int*)d_in[2];
  float* out = (float*)d_out;
  char* ws = (char*)d_ws;

  // ws: Ab 2MB | Tb 2MB | diag 32KB | rowp 8MB | colp 8MB | bsum 8KB
  ushort* Ab  = (ushort*)ws;
  ushort* Tb  = (ushort*)(ws + (size_t)NN * EE * 2);
  float* diag = (float*)(ws + (size_t)NN * EE * 4);
  float2* rowp = (float2*)(ws + (size_t)NN * EE * 4 + (size_t)NN * 4);
  float2* colp = (float2*)(ws + (size_t)NN * EE * 4 + (size_t)NN * 4 + (size_t)NN * 128 * 8);
  float* bsum = (float*)(ws + (size_t)NN * EE * 4 + (size_t)NN * 4 + (size_t)NN * 128 * 8 * 2);

  hipLaunchKernelGGL(lsl_cvt_kernel, dim3(NN * EE / 4 / 256), dim3(256), 0, stream, A, T, Ab, Tb, diag);
  hipLaunchKernelGGL(lsl_tile_kernel, dim3(4096), dim3(256), 0, stream, Ab, Tb, fids, rowp, colp);
  hipLaunchKernelGGL(lsl_merge_kernel, dim3(NN / 4), dim3(256), 0, stream, rowp, colp, diag, bsum);
  hipLaunchKernelGGL(lsl_final_kernel, dim3(1), dim3(256), 0, stream, bsum, out);
}

// Round 6
// 91.296 us; speedup vs baseline: 2.0144x; 1.1721x over previous
//
#include <hip/hip_runtime.h>
#include <hip/hip_bf16.h>
#include <math.h>

#define NN 8192
#define EE 128

static constexpr float INV_T = 1.0f / 0.07f;
static constexpr float LOG2E = 1.4426950408889634f;
static constexpr float LN2   = 0.6931471805599453f;
static constexpr float SENT  = -3.0e38f;

typedef __attribute__((ext_vector_type(8))) short fragAB;   // 8 bf16
typedef __attribute__((ext_vector_type(4))) float f32x4;

__device__ inline float fexp2(float x) { float r; asm("v_exp_f32 %0, %1" : "=v"(r) : "v"(x)); return r; }
__device__ inline float flog2(float x) { float r; asm("v_log_f32 %0, %1" : "=v"(r) : "v"(x)); return r; }

template<int CTRL>
__device__ inline float dpp_f(float x) {
  return __builtin_bit_cast(float,
      __builtin_amdgcn_update_dpp(0, __builtin_bit_cast(int, x), CTRL, 0xf, 0xf, true));
}
__device__ inline float red16_max(float x) {
  x = fmaxf(x, dpp_f<0xB1>(x));    // quad_perm [1,0,3,2]
  x = fmaxf(x, dpp_f<0x4E>(x));    // quad_perm [2,3,0,1]
  x = fmaxf(x, dpp_f<0x141>(x));   // row_half_mirror
  x = fmaxf(x, dpp_f<0x140>(x));   // row_mirror
  return x;
}
__device__ inline float red16_add(float x) {
  x += dpp_f<0xB1>(x); x += dpp_f<0x4E>(x); x += dpp_f<0x141>(x); x += dpp_f<0x140>(x);
  return x;
}

__device__ inline ushort f32_to_bf16_bits(float x) {
  union { float f; unsigned u; } c; c.f = x;
  unsigned u = c.u;
  u += 0x7fffu + ((u >> 16) & 1u);   // RNE
  return (ushort)(u >> 16);
}

// fp32 -> bf16 (A pre-scaled by 1/temp*log2e so scores are log2-domain),
// plus exact fp32 diagonal dot products (log2 units).
__global__ void lsl_cvt_kernel(const float* __restrict__ A, const float* __restrict__ T,
                               ushort* __restrict__ Ab, ushort* __restrict__ Tb,
                               float* __restrict__ diag) {
  const int t = blockIdx.x * 256 + threadIdx.x;
  const int i = t * 4;
  float4 a = *reinterpret_cast<const float4*>(A + i);
  float4 tt = *reinterpret_cast<const float4*>(T + i);
  ushort4 oa, ot;
  const float SC = INV_T * LOG2E;
  oa.x = f32_to_bf16_bits(a.x * SC); oa.y = f32_to_bf16_bits(a.y * SC);
  oa.z = f32_to_bf16_bits(a.z * SC); oa.w = f32_to_bf16_bits(a.w * SC);
  ot.x = f32_to_bf16_bits(tt.x); ot.y = f32_to_bf16_bits(tt.y);
  ot.z = f32_to_bf16_bits(tt.z); ot.w = f32_to_bf16_bits(tt.w);
  *reinterpret_cast<ushort4*>(Ab + i) = oa;
  *reinterpret_cast<ushort4*>(Tb + i) = ot;

  float pd = a.x * tt.x + a.y * tt.y + a.z * tt.z + a.w * tt.w;
  pd += __shfl_xor(pd, 1); pd += __shfl_xor(pd, 2); pd += __shfl_xor(pd, 4);
  pd += __shfl_xor(pd, 8); pd += __shfl_xor(pd, 16);
  if ((threadIdx.x & 31) == 0) diag[i >> 7] = pd * (INV_T * LOG2E);   // log2 units
}

#define LDFRAG(av, bv, ks)                                                        \
  _Pragma("unroll") for (int f = 0; f < 4; ++f) {                                 \
    av[f] = *reinterpret_cast<const fragAB*>(abase + f * (16 * EE) + (ks) * 32);  \
    bv[f] = *reinterpret_cast<const fragAB*>(bbase + f * (16 * EE) + (ks) * 32);  \
  }
#define MMAC(av, bv)                                                              \
  _Pragma("unroll") for (int fm = 0; fm < 4; ++fm)                                \
    _Pragma("unroll") for (int fn = 0; fn < 4; ++fn)                              \
      acc[fm][fn] = __builtin_amdgcn_mfma_f32_16x16x32_bf16(av[fm], bv[fn], acc[fm][fn], 0, 0, 0);

// WG = 128x128 (4 waves 2x2, one 64x64 sub-tile per wave). Fragment loads
// double-buffered (prefetch ks+1 before consuming ks). Partial layouts are
// [block][row] / [block][col] for coalesced 128B stores; merge kernel
// transposes through LDS.
__global__ __launch_bounds__(256, 3) void
lsl_tile_kernel(const ushort* __restrict__ Ab, const ushort* __restrict__ Tb,
                const int* __restrict__ fids,
                float2* __restrict__ rowp, float2* __restrict__ colp) {
  const int bid = blockIdx.x;
  const int swz = (bid & 7) * 512 + (bid >> 3);   // bijective XCD chunking (4096 WGs)
  const int tm = swz >> 6, tn = swz & 63;
  const int lane = threadIdx.x & 63;
  const int wid  = threadIdx.x >> 6;
  const int wm = wid >> 1, wn = wid & 1;
  const int rbase = tm * 128 + wm * 64;
  const int cbase = tn * 128 + wn * 64;
  const int lr = lane & 15, lg = lane >> 4;

  const ushort* abase = Ab + (size_t)(rbase + lr) * EE + lg * 8;
  const ushort* bbase = Tb + (size_t)(cbase + lr) * EE + lg * 8;

  f32x4 acc[4][4] = {};   // D: col = lane&15, row = (lane>>4)*4 + reg
  fragAB a0[4], b0[4], a1[4], b1[4];

  LDFRAG(a0, b0, 0)
  LDFRAG(a1, b1, 1)
  MMAC(a0, b0)
  LDFRAG(a0, b0, 2)
  MMAC(a1, b1)
  LDFRAG(a1, b1, 3)
  MMAC(a0, b0)
  MMAC(a1, b1)

  // fids loaded post-MFMA so live ranges stay off the main loop
  int fr[4][4], fc[4];
#pragma unroll
  for (int fm = 0; fm < 4; ++fm) {
    int4 v4 = *reinterpret_cast<const int4*>(fids + rbase + fm * 16 + lg * 4);
    fr[fm][0] = v4.x; fr[fm][1] = v4.y; fr[fm][2] = v4.z; fr[fm][3] = v4.w;
  }
#pragma unroll
  for (int fn = 0; fn < 4; ++fn) fc[fn] = fids[cbase + fn * 16 + lr];

  // branchless mask -> sentinel (diagonal kept; only possible when rbase == cbase)
  if (rbase == cbase) {
#pragma unroll
    for (int fm = 0; fm < 4; ++fm)
#pragma unroll
      for (int fn = 0; fn < 4; ++fn)
#pragma unroll
        for (int r = 0; r < 4; ++r) {
          bool keep = (fr[fm][r] != fc[fn]) || (fm == fn && lr == lg * 4 + r);
          acc[fm][fn][r] = keep ? acc[fm][fn][r] : SENT;
        }
  } else {
#pragma unroll
    for (int fm = 0; fm < 4; ++fm)
#pragma unroll
      for (int fn = 0; fn < 4; ++fn)
#pragma unroll
        for (int r = 0; r < 4; ++r)
          acc[fm][fn][r] = (fr[fm][r] != fc[fn]) ? acc[fm][fn][r] : SENT;
  }

  // row partials over this wave's 64 cols (own-max referenced)
  const int rblk = tn * 2 + wn;
#pragma unroll
  for (int fm = 0; fm < 4; ++fm)
#pragma unroll
    for (int r = 0; r < 4; ++r) {
      float m = fmaxf(fmaxf(acc[fm][0][r], acc[fm][1][r]), fmaxf(acc[fm][2][r], acc[fm][3][r]));
      m = red16_max(m);
      float s = fexp2(acc[fm][0][r] - m) + fexp2(acc[fm][1][r] - m)
              + fexp2(acc[fm][2][r] - m) + fexp2(acc[fm][3][r] - m);
      s = red16_add(s);
      if (lr == 0)
        rowp[(size_t)rblk * NN + (rbase + fm * 16 + lg * 4 + r)] = make_float2(m, s);
    }

  // col partials over this wave's 64 rows (own-max referenced)
  const int cblk = tm * 2 + wm;
#pragma unroll
  for (int fn = 0; fn < 4; ++fn) {
    float cm = SENT;
#pragma unroll
    for (int fm = 0; fm < 4; ++fm)
#pragma unroll
      for (int r = 0; r < 4; ++r) cm = fmaxf(cm, acc[fm][fn][r]);
    cm = fmaxf(cm, __shfl_xor(cm, 16));
    cm = fmaxf(cm, __shfl_xor(cm, 32));
    float c = 0.f;
#pragma unroll
    for (int fm = 0; fm < 4; ++fm)
#pragma unroll
      for (int r = 0; r < 4; ++r) c += fexp2(acc[fm][fn][r] - cm);
    c += __shfl_xor(c, 16);
    c += __shfl_xor(c, 32);
    if (lg == 0)
      colp[(size_t)cblk * NN + (cbase + fn * 16 + lr)] = make_float2(cm, c);
  }
}

// WG handles 32 samples: stage [128 blocks][32 samples] slab through padded LDS
// (coalesced global reads), 8 threads per sample merge 128 partials in 2 passes.
__global__ __launch_bounds__(256) void
lsl_merge_kernel(const float2* __restrict__ rowp, const float2* __restrict__ colp,
                 const float* __restrict__ diag, float* __restrict__ bsum) {
  __shared__ float2 sl[128 * 33];     // [b][di], pad 33 (33.8 KB)
  __shared__ float2 red[32][8];
  const int tid = threadIdx.x;
  const int ibase = blockIdx.x * 32;
  const int s = tid & 31, p = tid >> 5;

  float lse0 = 0.f, lse1 = 0.f;
#pragma unroll
  for (int pass = 0; pass < 2; ++pass) {
    const float2* __restrict__ src = pass ? colp : rowp;
#pragma unroll
    for (int k = 0; k < 16; ++k) {
      int L = tid + k * 256;          // 0..4095
      int b = L >> 5, di = L & 31;
      sl[b * 33 + di] = src[(size_t)b * NN + ibase + di];
    }
    __syncthreads();
    float m = SENT;
#pragma unroll
    for (int k = 0; k < 16; ++k) m = fmaxf(m, sl[(p * 16 + k) * 33 + s].x);
    float sum = 0.f;
#pragma unroll
    for (int k = 0; k < 16; ++k) {
      float2 v = sl[(p * 16 + k) * 33 + s];
      sum += v.y * fexp2(v.x - m);
    }
    red[s][p] = make_float2(m, sum);
    __syncthreads();
    if (p == 0) {
      float M = SENT;
#pragma unroll
      for (int k = 0; k < 8; ++k) M = fmaxf(M, red[s][k].x);
      float S = 0.f;
#pragma unroll
      for (int k = 0; k < 8; ++k) S += red[s][k].y * fexp2(red[s][k].x - M);
      if (pass == 0) lse0 = M + flog2(S); else lse1 = M + flog2(S);
    }
    __syncthreads();
  }

  if (tid < 32) {
    float loss = lse0 + lse1 - 2.f * diag[ibase + tid];   // log2 units
#pragma unroll
    for (int d = 1; d < 32; d <<= 1) loss += __shfl_xor(loss, d);
    if (tid == 0) bsum[blockIdx.x] = loss;
  }
}

__global__ __launch_bounds__(256) void
lsl_final_kernel(const float* __restrict__ bsum, float* __restrict__ out) {
  float v = bsum[threadIdx.x];
#pragma unroll
  for (int d = 1; d < 64; d <<= 1) v += __shfl_xor(v, d);
  __shared__ float l4[4];
  if ((threadIdx.x & 63) == 0) l4[threadIdx.x >> 6] = v;
  __syncthreads();
  if (threadIdx.x == 0) out[0] = (l4[0] + l4[1] + l4[2] + l4[3]) * (LN2 / (float)NN);
}

extern "C" void kernel_launch(void* const* d_in, const int* in_sizes, int n_in,
                              void* d_out, int out_size, void* d_ws, size_t ws_size,
                              hipStream_t stream) {
  const float* A = (const float*)d_in[0];
  const float* T = (const float*)d_in[1];
  const int* fids = (const int*)d_in[2];
  float* out = (float*)d_out;
  char* ws = (char*)d_ws;

  // ws: Ab 2MB | Tb 2MB | diag 32KB | rowp 8MB | colp 8MB | bsum 1KB
  ushort* Ab  = (ushort*)ws;
  ushort* Tb  = (ushort*)(ws + (size_t)NN * EE * 2);
  float* diag = (float*)(ws + (size_t)NN * EE * 4);
  float2* rowp = (float2*)(ws + (size_t)NN * EE * 4 + (size_t)NN * 4);
  float2* colp = (float2*)(ws + (size_t)NN * EE * 4 + (size_t)NN * 4 + (size_t)NN * 128 * 8);
  float* bsum = (float*)(ws + (size_t)NN * EE * 4 + (size_t)NN * 4 + (size_t)NN * 128 * 8 * 2);

  hipLaunchKernelGGL(lsl_cvt_kernel, dim3(NN * EE / 4 / 256), dim3(256), 0, stream, A, T, Ab, Tb, diag);
  hipLaunchKernelGGL(lsl_tile_kernel, dim3(4096), dim3(256), 0, stream, Ab, Tb, fids, rowp, colp);
  hipLaunchKernelGGL(lsl_merge_kernel, dim3(NN / 32), dim3(256), 0, stream, rowp, colp, diag, bsum);
  hipLaunchKernelGGL(lsl_final_kernel, dim3(1), dim3(256), 0, stream, bsum, out);
}